// Round 13
// baseline (343.676 us; speedup 1.0000x reference)
//
#include <hip/hip_runtime.h>
#include <math.h>

#define Sn 4
#define Bn 8
#define Ln 512
#define Dn 128
#define Hn 128
#define NOPn 64
#define Wn 2048

// ESTABLISHED: inputs fp32 insertion order; output fp32; bf16-space compare
// (thr 3.6e-2); ws = 512MB; harness tax ~220-260us/iter; poison fill 78us.
// R21 354. R27 350.6 (bf16 upWbf). R28 345.0 (wide loads). R30 339.2 (XCD
// swizzle). R29/R31 FAIL (block shape changes). R32 FAIL 346.6: ballot-fused
// gathers were ushort2-narrow (1 row in flight) -- conflated with the atomic
// removal win. R33 334.9 (BEST): dual GEMM -> bf16 MFMA 16x16x32 (layout
// verified: absmax unchanged).
// R34 (this): (a) oph GEMM -> same MFMA path (prep was bounded by its 8
// fp32 oph blocks); (b) mega: ballot-walk gathers WITH R28's width -- wave
// scans its quarter (no LDS index list, no same-address atomics, no
// post-scan barrier), walks masks 2 set-bits/step: hl=0 loads row o0,
// hl=1 row o1, ushort4/lane, shfl_xor(32) merge. 2 rows in flight kept.

__device__ __forceinline__ float bf2f(unsigned short u) {
    return __uint_as_float(((unsigned int)u) << 16);
}
__device__ __forceinline__ float bflo(unsigned int u) {
    return __uint_as_float(u << 16);
}
__device__ __forceinline__ float bfhi(unsigned int u) {
    return __uint_as_float(u & 0xFFFF0000u);
}
__device__ __forceinline__ unsigned short f2bf(float f) {
    unsigned int u = __float_as_uint(f);
    return (unsigned short)((u + 0x7FFFu + ((u >> 16) & 1u)) >> 16);  // RNE
}

typedef __attribute__((ext_vector_type(8))) short bf16x8;
typedef __attribute__((ext_vector_type(4))) float f32x4;

// ---------------------------------------------------------------------------
// prep_k: blockIdx branches.
//   0..255   : dual GEMM tile via bf16 MFMA (wkh/wsh from word_outputs)
//   256..263 : op-embedding GEMM tile via bf16 MFMA (oph)
//   264..271 : compact pooled indices for b = bid-264 (cap 512)
//   272      : zero gwacc
//   273..274 : convert upW (384x128 fp32) -> upWbf (bf16)
// ---------------------------------------------------------------------------
__global__ __launch_bounds__(256) void prep_k(const float* __restrict__ A,
                                              const float* __restrict__ W1,
                                              const float* __restrict__ W2,
                                              const float* __restrict__ b1,
                                              const float* __restrict__ b2,
                                              unsigned short* __restrict__ C1,
                                              unsigned short* __restrict__ C2,
                                              const float* __restrict__ ope,
                                              const float* __restrict__ owW,
                                              const float* __restrict__ owb,
                                              unsigned short* __restrict__ oph,
                                              const float* __restrict__ goal,
                                              const float* __restrict__ wes,
                                              int* __restrict__ widx,
                                              int* __restrict__ wcnt,
                                              float* __restrict__ gwacc,
                                              const float* __restrict__ upW,
                                              unsigned short* __restrict__ upWbf) {
    __shared__ __align__(16) unsigned char smem[33792];
    const int bid = blockIdx.x, tid = threadIdx.x;

    if (bid < 264) {  // ---- GEMM tiles via MFMA (dual for <256, single for oph) ----
        unsigned short (*WT)[132] = reinterpret_cast<unsigned short(*)[132]>(smem);
        const bool dual = bid < 256;
        const int m0 = dual ? bid * 64 : (bid - 256) * 64;
        const float* Asrc = dual ? A : ope;
        const int lane = tid & 63, wr = tid >> 6;
        const int rloc = lane & 15, bsel = lane >> 4;

        // hoist A fragments (row m0+wr*16+rloc), two-half k-layout per ks
        bf16x8 af[4];
        const float* Arow = Asrc + (size_t)(m0 + wr * 16 + rloc) * 128;
#pragma unroll
        for (int ks = 0; ks < 4; ++ks) {
            float4 a0 = *reinterpret_cast<const float4*>(Arow + ks * 32 + 4 * bsel);
            float4 a1 = *reinterpret_cast<const float4*>(Arow + ks * 32 + 16 + 4 * bsel);
            af[ks][0] = (short)f2bf(a0.x); af[ks][1] = (short)f2bf(a0.y);
            af[ks][2] = (short)f2bf(a0.z); af[ks][3] = (short)f2bf(a0.w);
            af[ks][4] = (short)f2bf(a1.x); af[ks][5] = (short)f2bf(a1.y);
            af[ks][6] = (short)f2bf(a1.z); af[ks][7] = (short)f2bf(a1.w);
        }

        const int nmat = dual ? 2 : 1;
        for (int mat = 0; mat < nmat; ++mat) {
            const float* Wsrc = dual ? (mat ? W2 : W1) : owW;
            const float* bias = dual ? (mat ? b2 : b1) : owb;
            unsigned short* Cdst = dual ? (mat ? C2 : C1) : oph;
            __syncthreads();  // protect WT before restage
            for (int idx = tid; idx < 128 * 128; idx += 256) {
                const int k = idx >> 7, c = idx & 127;
                WT[c][k] = f2bf(Wsrc[k * 128 + c]);
            }
            __syncthreads();

            f32x4 acc[8];
#pragma unroll
            for (int tl = 0; tl < 8; ++tl) acc[tl] = (f32x4){0.f, 0.f, 0.f, 0.f};
#pragma unroll
            for (int ks = 0; ks < 4; ++ks) {
#pragma unroll
                for (int tl = 0; tl < 8; ++tl) {
                    const unsigned short* p = &WT[tl * 16 + rloc][ks * 32 + 4 * bsel];
                    bf16x8 bfv;
#pragma unroll
                    for (int j = 0; j < 4; ++j) {
                        bfv[j]     = (short)p[j];
                        bfv[4 + j] = (short)p[16 + j];
                    }
                    acc[tl] = __builtin_amdgcn_mfma_f32_16x16x32_bf16(
                        af[ks], bfv, acc[tl], 0, 0, 0);
                }
            }
            // C/D: col = lane&15, row = (lane>>4)*4 + q  [verified m89/m91]
#pragma unroll
            for (int tl = 0; tl < 8; ++tl) {
                const int col = tl * 16 + rloc;
                const float bv = bias[col];
#pragma unroll
                for (int q = 0; q < 4; ++q) {
                    const int row = m0 + wr * 16 + bsel * 4 + q;
                    Cdst[(size_t)row * 128 + col] = f2bf(acc[tl][q] + bv);
                }
            }
        }
    } else if (bid < 272) {  // ---- compact (cap 512) ----
        int* cnt = reinterpret_cast<int*>(smem);
        const int b = bid - 264;
        if (tid == 0) *cnt = 0;
        __syncthreads();
#pragma unroll
        for (int j = 0; j < 8; ++j) {
            const int w = tid * 8 + j;
            if (goal[b * Wn + w] != 0.f && wes[b * Wn + w] != 0.f) {
                const int p = atomicAdd(cnt, 1);
                if (p < 512) widx[b * 512 + p] = w;
            }
        }
        __syncthreads();
        if (tid == 0) wcnt[b] = *cnt < 512 ? *cnt : 512;
    } else if (bid == 272) {  // ---- zero gwacc ----
        for (int idx = tid; idx < 1024; idx += 256) gwacc[idx] = 0.f;
    } else {  // ---- upW -> bf16 (2 blocks, 24576 elems each) ----
        const int base = (bid - 273) * 24576;
        for (int e = base + tid * 4; e < base + 24576; e += 1024) {
            float4 v = *reinterpret_cast<const float4*>(upW + e);
            alignas(8) unsigned short u[4] = {f2bf(v.x), f2bf(v.y), f2bf(v.z), f2bf(v.w)};
            *reinterpret_cast<uint2*>(upWbf + e) = *reinterpret_cast<const uint2*>(u);
        }
    }
}

// ---------------------------------------------------------------------------
// mega_agg10: one block per pooled slot, XCD-swizzled b=bid&7, 4 waves/slot.
// Ballot-walk gathers with 2-rows-in-flight: wave wv scans words
// [wv*512,+512) of ww&wem (float4), ballots each j; walks each mask two
// set-bits per step (hl=0 -> o0, hl=1 -> o1), ushort4 per lane (c=lane&31),
// shfl_xor(32) merge. Same for dep quarter -> wsh. No LDS index lists, no
// LDS atomics, no post-scan barrier. p4/p5 unchanged from R30.
// ---------------------------------------------------------------------------
__global__ __launch_bounds__(256) void mega_agg10(const int* __restrict__ widx,
                                                  const int* __restrict__ wcnt,
                                                  const float* __restrict__ ww,
                                                  const float* __restrict__ wem,
                                                  const float* __restrict__ dep,
                                                  const float* __restrict__ wop,
                                                  const unsigned short* __restrict__ oph,
                                                  const unsigned short* __restrict__ wkh,
                                                  const unsigned short* __restrict__ wsh,
                                                  const unsigned short* __restrict__ upWbf,
                                                  const float* __restrict__ upb,
                                                  float* __restrict__ gwacc) {
    const int bid = blockIdx.x;
    const int b = bid & 7, i = bid >> 3;   // XCD swizzle: batch -> XCD
    if (i >= wcnt[b]) return;              // uniform exit
    const int w_dst = widx[b * 512 + i];
    const int t = threadIdx.x;
    const int lane = t & 63, wv = t >> 6;
    const int hl = lane >> 5, c = lane & 31;

    __shared__ float part1[4][128];
    __shared__ float part2[4][128];
    __shared__ float nbL[384];
    __shared__ float gp16[16][128];

    const int sD = w_dst >> 9, lD = w_dst & 511;

    // --- slot1: scan quarter of ww&wem + ballot-walk gather (2 in flight) ---
    {
        const float* wwr = ww  + ((size_t)(b * Wn + w_dst)) * Wn;
        const float* wmr = wem + ((size_t)(b * Wn + w_dst)) * Wn;
        float a0 = 0.f, a1 = 0.f, a2 = 0.f, a3 = 0.f;
#pragma unroll
        for (int r = 0; r < 2; ++r) {
            const int e0 = wv * 512 + r * 256 + lane * 4;
            float4 v = *reinterpret_cast<const float4*>(wwr + e0);
            float4 m = *reinterpret_cast<const float4*>(wmr + e0);
            float vv[4] = {v.x, v.y, v.z, v.w};
            float mm[4] = {m.x, m.y, m.z, m.w};
#pragma unroll
            for (int j = 0; j < 4; ++j) {
                unsigned long long bal = __ballot(vv[j] != 0.f && mm[j] != 0.f);
                const int base = wv * 512 + r * 256 + j;
                while (bal) {
                    const int o0 = __ffsll(bal) - 1;
                    bal &= bal - 1;
                    int o1 = -1;
                    if (bal) { o1 = __ffsll(bal) - 1; bal &= bal - 1; }
                    const int o = hl ? o1 : o0;
                    if (o >= 0) {
                        const int w = base + 4 * o;
                        const int s = w >> 9, l = w & 511;
                        ushort4 x = *reinterpret_cast<const ushort4*>(
                            wkh + ((size_t)((s * Bn + b) * Ln + l)) * Hn + c * 4);
                        a0 += bf2f(x.x); a1 += bf2f(x.y);
                        a2 += bf2f(x.z); a3 += bf2f(x.w);
                    }
                }
            }
        }
        a0 += __shfl_xor(a0, 32); a1 += __shfl_xor(a1, 32);
        a2 += __shfl_xor(a2, 32); a3 += __shfl_xor(a3, 32);
        if (hl == 0) {
            part1[wv][c * 4 + 0] = a0; part1[wv][c * 4 + 1] = a1;
            part1[wv][c * 4 + 2] = a2; part1[wv][c * 4 + 3] = a3;
        }
    }

    // --- slot2: scan quarter of dep + ballot-walk gather (2 in flight) ---
    {
        const float* dr = dep + ((size_t)((sD * Bn + b) * Ln + lD)) * Ln;
        const unsigned short* basep = wsh + (size_t)((sD * Bn + b) * Ln) * Hn + c * 4;
        float a0 = 0.f, a1 = 0.f, a2 = 0.f, a3 = 0.f;
        const int e0 = wv * 128 + lane * 2;
        float2 v = *reinterpret_cast<const float2*>(dr + e0);
        float vv[2] = {v.x, v.y};
#pragma unroll
        for (int j = 0; j < 2; ++j) {
            unsigned long long bal = __ballot(vv[j] != 0.f);
            const int lbase = wv * 128 + j;
            while (bal) {
                const int o0 = __ffsll(bal) - 1;
                bal &= bal - 1;
                int o1 = -1;
                if (bal) { o1 = __ffsll(bal) - 1; bal &= bal - 1; }
                const int o = hl ? o1 : o0;
                if (o >= 0) {
                    const int l = lbase + 2 * o;
                    ushort4 x = *reinterpret_cast<const ushort4*>(basep + (size_t)l * Hn);
                    a0 += bf2f(x.x); a1 += bf2f(x.y);
                    a2 += bf2f(x.z); a3 += bf2f(x.w);
                }
            }
        }
        a0 += __shfl_xor(a0, 32); a1 += __shfl_xor(a1, 32);
        a2 += __shfl_xor(a2, 32); a3 += __shfl_xor(a3, 32);
        if (hl == 0) {
            part2[wv][c * 4 + 0] = a0; part2[wv][c * 4 + 1] = a1;
            part2[wv][c * 4 + 2] = a2; part2[wv][c * 4 + 3] = a3;
        }
    }

    // --- slot0 (wave 3): operator aggregation -> nbL[0:128] ---
    if (wv == 3) {
        const float m_op = wop[((size_t)(b * Wn + w_dst)) * NOPn + lane];
        unsigned long long bal = __ballot(m_op != 0.f);
        float a0 = 0.f, a1 = 0.f;
        const unsigned short* base = oph + (size_t)b * NOPn * Hn + 2 * lane;
        while (bal) {
            const int o = __ffsll(bal) - 1;
            bal &= bal - 1;
            ushort2 v = *reinterpret_cast<const ushort2*>(base + o * Hn);
            a0 += bf2f(v.x);
            a1 += bf2f(v.y);
        }
        float ss = a0 * a0 + a1 * a1;
#pragma unroll
        for (int off = 1; off < 64; off <<= 1) ss += __shfl_xor(ss, off);
        const float sc = 1.f / (sqrtf(ss) + 1e-30f);
        nbL[2 * lane]     = a0 * sc;
        nbL[2 * lane + 1] = a1 * sc;
    }
    __syncthreads();

    // --- p4: reduce+normalize slot1 (wave0) and slot2 (wave1) ---
    if (wv == 0) {
        float s0 = 0.f, s1 = 0.f;
#pragma unroll
        for (int q = 0; q < 4; ++q) {
            s0 += part1[q][2 * lane];
            s1 += part1[q][2 * lane + 1];
        }
        float ss = s0 * s0 + s1 * s1;
#pragma unroll
        for (int off = 1; off < 64; off <<= 1) ss += __shfl_xor(ss, off);
        const float sc = 1.f / (sqrtf(ss) + 1e-30f);
        nbL[128 + 2 * lane]     = s0 * sc;
        nbL[128 + 2 * lane + 1] = s1 * sc;
    } else if (wv == 1) {
        float s0 = 0.f, s1 = 0.f;
#pragma unroll
        for (int q = 0; q < 4; ++q) {
            s0 += part2[q][2 * lane];
            s1 += part2[q][2 * lane + 1];
        }
        float ss = s0 * s0 + s1 * s1;
#pragma unroll
        for (int off = 1; off < 64; off <<= 1) ss += __shfl_xor(ss, off);
        const float sc = 1.f / (sqrtf(ss) + 1e-30f);
        nbL[256 + 2 * lane]     = s0 * sc;
        nbL[256 + 2 * lane + 1] = s1 * sc;
    }
    __syncthreads();

    // --- p5: wide-load up-GEMV. thread (i=t&15, j=t>>4): 8 dims i*8..i*8+7,
    // k = r*16 + j over 24 rounds; uint4 load = 8 bf16 per round. ---
    {
        const int i8 = (t & 15) * 8, j = t >> 4;
        float a[8] = {};
#pragma unroll
        for (int r = 0; r < 24; ++r) {
            const int k = r * 16 + j;
            const uint4 w = *reinterpret_cast<const uint4*>(upWbf + (size_t)k * 128 + i8);
            const float x = nbL[k];
            a[0] = fmaf(x, bflo(w.x), a[0]); a[1] = fmaf(x, bfhi(w.x), a[1]);
            a[2] = fmaf(x, bflo(w.y), a[2]); a[3] = fmaf(x, bfhi(w.y), a[3]);
            a[4] = fmaf(x, bflo(w.z), a[4]); a[5] = fmaf(x, bfhi(w.z), a[5]);
            a[6] = fmaf(x, bflo(w.w), a[6]); a[7] = fmaf(x, bfhi(w.w), a[7]);
        }
#pragma unroll
        for (int q = 0; q < 8; ++q) gp16[j][i8 + q] = a[q];
    }
    __syncthreads();
    if (t < 128) {
        float g = upb[t];
#pragma unroll
        for (int j = 0; j < 16; ++j) g += gp16[j][t];
        g = fmaxf(g, 0.f);
        atomicAdd(&gwacc[b * 128 + t], g);
    }
}

// ---------------------------------------------------------------------------
// final4: read pooled sums, mean, two GEMVs, gates. 8 blocks x 128 thr.
// ---------------------------------------------------------------------------
__global__ __launch_bounds__(128) void final4_k(const int* __restrict__ wcnt,
                                                const float* __restrict__ gwacc,
                                                const float* __restrict__ nh,
                                                const float* __restrict__ wgW,
                                                const float* __restrict__ wgb,
                                                const float* __restrict__ fgW,
                                                const float* __restrict__ fgb,
                                                float* __restrict__ out) {
    const int b = blockIdx.x, t = threadIdx.x;
    __shared__ float gw[Dn], nhs[Dn];
    const float inv = 1.f / ((float)wcnt[b] + 1e-30f);
    gw[t]  = gwacc[b * Dn + t] * inv;
    nhs[t] = nh[b * Dn + t];
    __syncthreads();
    float gu = wgb[t];
    for (int d = 0; d < Dn; ++d) gu = fmaf(gw[d], wgW[d * Dn + t], gu);
    gu = fmaxf(gu, 0.f);
    float fg = fgb[t];
    for (int d = 0; d < Dn; ++d) fg = fmaf(gw[d], fgW[d * Dn + t], fg);
    for (int d = 0; d < Dn; ++d) fg = fmaf(nhs[d], fgW[(Dn + d) * Dn + t], fg);
    const float forget = 1.f / (1.f + expf(-fg));
    out[b * Dn + t] = fmaxf(forget, 0.1f) * nhs[t] + (1.f - forget) * gu;
}

// ---------------------------------------------------------------------------
extern "C" void kernel_launch(void* const* d_in, const int* in_sizes, int n_in,
                              void* d_out, int out_size, void* d_ws, size_t ws_size,
                              hipStream_t stream) {
    (void)in_sizes; (void)n_in; (void)out_size; (void)ws_size;
    const float* word_outputs        = (const float*)d_in[0];
    const float* node_hidden         = (const float*)d_in[1];
    const float* op_embedding        = (const float*)d_in[2];
    const float* word_operator       = (const float*)d_in[3];
    const float* word_word           = (const float*)d_in[4];
    const float* depend_relation     = (const float*)d_in[5];
    const float* word_exist_matrix   = (const float*)d_in[6];
    const float* word_exist_sequence = (const float*)d_in[7];
    const float* goal_word           = (const float*)d_in[8];
    const float* o_w_W = (const float*)d_in[9];
    const float* o_w_b = (const float*)d_in[10];
    const float* wk_W  = (const float*)d_in[11];
    const float* wk_b  = (const float*)d_in[12];
    const float* ws_W  = (const float*)d_in[13];
    const float* ws_b  = (const float*)d_in[14];
    const float* up_W  = (const float*)d_in[15];
    const float* up_b  = (const float*)d_in[16];
    const float* wg_W  = (const float*)d_in[17];
    const float* wg_b  = (const float*)d_in[18];
    const float* fg_W  = (const float*)d_in[19];
    const float* fg_b  = (const float*)d_in[20];
    float* out = (float*)d_out;

    char* ws = (char*)d_ws;
    unsigned short* oph   = (unsigned short*)(ws + 0);                      // 128 KB
    unsigned short* wkh   = (unsigned short*)(ws + (1u << 20));             // 4 MB
    unsigned short* wsh   = (unsigned short*)(ws + (5u << 20));             // 4 MB
    int* widx             = (int*)(ws + (9u << 20));                        // 16 KB
    int* wcnt             = (int*)(ws + (9u << 20) + 32768);                // 32 B
    float* gwacc          = (float*)(ws + (9u << 20) + 65536);              // 4 KB
    unsigned short* upWbf = (unsigned short*)(ws + (9u << 20) + 131072);    // 96 KB

    prep_k<<<275, 256, 0, stream>>>(word_outputs, wk_W, ws_W, wk_b, ws_b, wkh, wsh,
                                    op_embedding, o_w_W, o_w_b, oph,
                                    goal_word, word_exist_sequence, widx, wcnt, gwacc,
                                    up_W, upWbf);
    mega_agg10<<<4096, 256, 0, stream>>>(widx, wcnt, word_word, word_exist_matrix,
                                         depend_relation, word_operator, oph, wkh, wsh,
                                         upWbf, up_b, gwacc);
    final4_k<<<8, 128, 0, stream>>>(wcnt, gwacc, node_hidden,
                                    wg_W, wg_b, fg_W, fg_b, out);
}

// Round 15
// 335.791 us; speedup vs baseline: 1.0235x; 1.0235x over previous
//
#include <hip/hip_runtime.h>
#include <math.h>

#define Sn 4
#define Bn 8
#define Ln 512
#define Dn 128
#define Hn 128
#define NOPn 64
#define Wn 2048

// ESTABLISHED: inputs fp32 insertion order; output fp32; bf16-space compare
// (thr 3.6e-2); ws = 512MB; harness tax ~220-260us/iter; poison fill 78us.
// R21 354. R27 350.6 (bf16 upWbf). R28 345.0 (wide loads). R30 339.2 (XCD
// swizzle). R33 334.9 (BEST): dual GEMM -> bf16 MFMA. R29/R31 FAIL (block
// shape). R32 FAIL 346.6 / R34 FAIL 343.7: ballot-walk gathers (serial
// mask-chain; at most 2 rows in flight) lose to R30's index-list loop
// (independent iterations, compiler-prefetchable). MEGA FROZEN at R30 shape.
// R35 (R14 was an infra failure -- container died; resubmit unchanged):
// R33 + oph-MFMA + float4 WT staging (16 iters/thread vs 64 scalar).
// Mega = R30 verbatim.

__device__ __forceinline__ float bf2f(unsigned short u) {
    return __uint_as_float(((unsigned int)u) << 16);
}
__device__ __forceinline__ float bflo(unsigned int u) {
    return __uint_as_float(u << 16);
}
__device__ __forceinline__ float bfhi(unsigned int u) {
    return __uint_as_float(u & 0xFFFF0000u);
}
__device__ __forceinline__ unsigned short f2bf(float f) {
    unsigned int u = __float_as_uint(f);
    return (unsigned short)((u + 0x7FFFu + ((u >> 16) & 1u)) >> 16);  // RNE
}

typedef __attribute__((ext_vector_type(8))) short bf16x8;
typedef __attribute__((ext_vector_type(4))) float f32x4;

// ---------------------------------------------------------------------------
// prep_k: blockIdx branches.
//   0..255   : dual GEMM tile via bf16 MFMA (wkh/wsh from word_outputs)
//   256..263 : op-embedding GEMM tile via bf16 MFMA (oph)
//   264..271 : compact pooled indices for b = bid-264 (cap 512)
//   272      : zero gwacc
//   273..274 : convert upW (384x128 fp32) -> upWbf (bf16)
// ---------------------------------------------------------------------------
__global__ __launch_bounds__(256) void prep_k(const float* __restrict__ A,
                                              const float* __restrict__ W1,
                                              const float* __restrict__ W2,
                                              const float* __restrict__ b1,
                                              const float* __restrict__ b2,
                                              unsigned short* __restrict__ C1,
                                              unsigned short* __restrict__ C2,
                                              const float* __restrict__ ope,
                                              const float* __restrict__ owW,
                                              const float* __restrict__ owb,
                                              unsigned short* __restrict__ oph,
                                              const float* __restrict__ goal,
                                              const float* __restrict__ wes,
                                              int* __restrict__ widx,
                                              int* __restrict__ wcnt,
                                              float* __restrict__ gwacc,
                                              const float* __restrict__ upW,
                                              unsigned short* __restrict__ upWbf) {
    __shared__ __align__(16) unsigned char smem[33792];
    const int bid = blockIdx.x, tid = threadIdx.x;

    if (bid < 264) {  // ---- GEMM tiles via MFMA (dual for <256, single for oph) ----
        unsigned short (*WT)[132] = reinterpret_cast<unsigned short(*)[132]>(smem);
        const bool dual = bid < 256;
        const int m0 = dual ? bid * 64 : (bid - 256) * 64;
        const float* Asrc = dual ? A : ope;
        const int lane = tid & 63, wr = tid >> 6;
        const int rloc = lane & 15, bsel = lane >> 4;

        // hoist A fragments (row m0+wr*16+rloc), two-half k-layout per ks
        bf16x8 af[4];
        const float* Arow = Asrc + (size_t)(m0 + wr * 16 + rloc) * 128;
#pragma unroll
        for (int ks = 0; ks < 4; ++ks) {
            float4 a0 = *reinterpret_cast<const float4*>(Arow + ks * 32 + 4 * bsel);
            float4 a1 = *reinterpret_cast<const float4*>(Arow + ks * 32 + 16 + 4 * bsel);
            af[ks][0] = (short)f2bf(a0.x); af[ks][1] = (short)f2bf(a0.y);
            af[ks][2] = (short)f2bf(a0.z); af[ks][3] = (short)f2bf(a0.w);
            af[ks][4] = (short)f2bf(a1.x); af[ks][5] = (short)f2bf(a1.y);
            af[ks][6] = (short)f2bf(a1.z); af[ks][7] = (short)f2bf(a1.w);
        }

        const int nmat = dual ? 2 : 1;
        for (int mat = 0; mat < nmat; ++mat) {
            const float* Wsrc = dual ? (mat ? W2 : W1) : owW;
            const float* bias = dual ? (mat ? b2 : b1) : owb;
            unsigned short* Cdst = dual ? (mat ? C2 : C1) : oph;
            __syncthreads();  // protect WT before restage
            // float4 staging: 16 iters/thread, 1 vector load + 4 LDS writes
            for (int idx = tid * 4; idx < 128 * 128; idx += 1024) {
                const int k = idx >> 7, c = idx & 127;
                float4 v = *reinterpret_cast<const float4*>(Wsrc + (size_t)k * 128 + c);
                WT[c + 0][k] = f2bf(v.x);
                WT[c + 1][k] = f2bf(v.y);
                WT[c + 2][k] = f2bf(v.z);
                WT[c + 3][k] = f2bf(v.w);
            }
            __syncthreads();

            f32x4 acc[8];
#pragma unroll
            for (int tl = 0; tl < 8; ++tl) acc[tl] = (f32x4){0.f, 0.f, 0.f, 0.f};
#pragma unroll
            for (int ks = 0; ks < 4; ++ks) {
#pragma unroll
                for (int tl = 0; tl < 8; ++tl) {
                    const unsigned short* p = &WT[tl * 16 + rloc][ks * 32 + 4 * bsel];
                    bf16x8 bfv;
#pragma unroll
                    for (int j = 0; j < 4; ++j) {
                        bfv[j]     = (short)p[j];
                        bfv[4 + j] = (short)p[16 + j];
                    }
                    acc[tl] = __builtin_amdgcn_mfma_f32_16x16x32_bf16(
                        af[ks], bfv, acc[tl], 0, 0, 0);
                }
            }
            // C/D: col = lane&15, row = (lane>>4)*4 + q  [verified m89/m91]
#pragma unroll
            for (int tl = 0; tl < 8; ++tl) {
                const int col = tl * 16 + rloc;
                const float bv = bias[col];
#pragma unroll
                for (int q = 0; q < 4; ++q) {
                    const int row = m0 + wr * 16 + bsel * 4 + q;
                    Cdst[(size_t)row * 128 + col] = f2bf(acc[tl][q] + bv);
                }
            }
        }
    } else if (bid < 272) {  // ---- compact (cap 512) ----
        int* cnt = reinterpret_cast<int*>(smem);
        const int b = bid - 264;
        if (tid == 0) *cnt = 0;
        __syncthreads();
#pragma unroll
        for (int j = 0; j < 8; ++j) {
            const int w = tid * 8 + j;
            if (goal[b * Wn + w] != 0.f && wes[b * Wn + w] != 0.f) {
                const int p = atomicAdd(cnt, 1);
                if (p < 512) widx[b * 512 + p] = w;
            }
        }
        __syncthreads();
        if (tid == 0) wcnt[b] = *cnt < 512 ? *cnt : 512;
    } else if (bid == 272) {  // ---- zero gwacc ----
        for (int idx = tid; idx < 1024; idx += 256) gwacc[idx] = 0.f;
    } else {  // ---- upW -> bf16 (2 blocks, 24576 elems each) ----
        const int base = (bid - 273) * 24576;
        for (int e = base + tid * 4; e < base + 24576; e += 1024) {
            float4 v = *reinterpret_cast<const float4*>(upW + e);
            alignas(8) unsigned short u[4] = {f2bf(v.x), f2bf(v.y), f2bf(v.z), f2bf(v.w)};
            *reinterpret_cast<uint2*>(upWbf + e) = *reinterpret_cast<const uint2*>(u);
        }
    }
}

// ---------------------------------------------------------------------------
// mega_agg7 (R30, frozen): one block per pooled slot, XCD-swizzled b=bid&7.
// Index-list scan (LDS atomics) + wide gathers (ushort4/lane, 2 rows per
// wave in flight via hl) + uint4 GEMV w/ [16][128] LDS tile. 3 barriers.
// ---------------------------------------------------------------------------
__global__ __launch_bounds__(256) void mega_agg7(const int* __restrict__ widx,
                                                 const int* __restrict__ wcnt,
                                                 const float* __restrict__ ww,
                                                 const float* __restrict__ wem,
                                                 const float* __restrict__ dep,
                                                 const float* __restrict__ wop,
                                                 const unsigned short* __restrict__ oph,
                                                 const unsigned short* __restrict__ wkh,
                                                 const unsigned short* __restrict__ wsh,
                                                 const unsigned short* __restrict__ upWbf,
                                                 const float* __restrict__ upb,
                                                 float* __restrict__ gwacc) {
    const int bid = blockIdx.x;
    const int b = bid & 7, i = bid >> 3;  // XCD swizzle: batch -> XCD
    if (i >= wcnt[b]) return;             // uniform exit
    const int w_dst = widx[b * 512 + i];
    const int t = threadIdx.x;
    const int lane = t & 63, wv = t >> 6;

    __shared__ int kidx[512];
    __shared__ int sidx[256];
    __shared__ int kn, sn;
    __shared__ float part1[4][128];
    __shared__ float part2[4][128];
    __shared__ float nbL[384];
    __shared__ float gp16[16][128];
    if (t == 0) { kn = 0; sn = 0; }
    __syncthreads();

    // --- p1: fused ww & wem row streams + dep row scan ---
    const float* wwr = ww  + ((size_t)(b * Wn + w_dst)) * Wn;
    const float* wmr = wem + ((size_t)(b * Wn + w_dst)) * Wn;
#pragma unroll
    for (int q = 0; q < 2; ++q) {
        const int e0 = q * 1024 + t * 4;
        float4 v = *reinterpret_cast<const float4*>(wwr + e0);
        float4 m = *reinterpret_cast<const float4*>(wmr + e0);
        float vv[4] = {v.x, v.y, v.z, v.w};
        float mm[4] = {m.x, m.y, m.z, m.w};
#pragma unroll
        for (int j = 0; j < 4; ++j)
            if (vv[j] != 0.f && mm[j] != 0.f) {
                int p = atomicAdd(&kn, 1);
                if (p < 512) kidx[p] = e0 + j;
            }
    }
    const int sD = w_dst >> 9, lD = w_dst & 511;
    if (t < 128) {
        const float* dr = dep + ((size_t)((sD * Bn + b) * Ln + lD)) * Ln + t * 4;
        float4 v = *reinterpret_cast<const float4*>(dr);
        float vv[4] = {v.x, v.y, v.z, v.w};
#pragma unroll
        for (int j = 0; j < 4; ++j)
            if (vv[j] != 0.f) {
                int p = atomicAdd(&sn, 1);
                if (p < 256) sidx[p] = t * 4 + j;
            }
    }
    float m_op = 0.f;
    if (wv == 3) m_op = wop[((size_t)(b * Wn + w_dst)) * NOPn + lane];
    __syncthreads();

    const int nk = kn < 512 ? kn : 512;
    const int ns = sn < 256 ? sn : 256;

    // --- p3: gathers (ushort4/lane, 2 rows per wave per iteration) ---
    {   // slot1
        const int hl = lane >> 5, c = lane & 31;
        float a0 = 0.f, a1 = 0.f, a2 = 0.f, a3 = 0.f;
        for (int p = wv * 2 + hl; p < nk; p += 8) {
            const int w = kidx[p];
            const int s = w >> 9, l = w & 511;
            ushort4 x = *reinterpret_cast<const ushort4*>(
                wkh + ((size_t)((s * Bn + b) * Ln + l)) * Hn + c * 4);
            a0 += bf2f(x.x); a1 += bf2f(x.y); a2 += bf2f(x.z); a3 += bf2f(x.w);
        }
        a0 += __shfl_xor(a0, 32); a1 += __shfl_xor(a1, 32);
        a2 += __shfl_xor(a2, 32); a3 += __shfl_xor(a3, 32);
        if (hl == 0) {
            part1[wv][c * 4 + 0] = a0; part1[wv][c * 4 + 1] = a1;
            part1[wv][c * 4 + 2] = a2; part1[wv][c * 4 + 3] = a3;
        }
    }
    {   // slot2
        const int hl = lane >> 5, c = lane & 31;
        const unsigned short* base = wsh + (size_t)((sD * Bn + b) * Ln) * Hn + c * 4;
        float a0 = 0.f, a1 = 0.f, a2 = 0.f, a3 = 0.f;
        for (int p = wv * 2 + hl; p < ns; p += 8) {
            ushort4 x = *reinterpret_cast<const ushort4*>(base + (size_t)sidx[p] * Hn);
            a0 += bf2f(x.x); a1 += bf2f(x.y); a2 += bf2f(x.z); a3 += bf2f(x.w);
        }
        a0 += __shfl_xor(a0, 32); a1 += __shfl_xor(a1, 32);
        a2 += __shfl_xor(a2, 32); a3 += __shfl_xor(a3, 32);
        if (hl == 0) {
            part2[wv][c * 4 + 0] = a0; part2[wv][c * 4 + 1] = a1;
            part2[wv][c * 4 + 2] = a2; part2[wv][c * 4 + 3] = a3;
        }
    }
    if (wv == 3) {  // slot0 -> nbL[0:128]
        unsigned long long bal = __ballot(m_op != 0.f);
        float a0 = 0.f, a1 = 0.f;
        const unsigned short* base = oph + (size_t)b * NOPn * Hn + 2 * lane;
        while (bal) {
            const int o = __ffsll(bal) - 1;
            bal &= bal - 1;
            ushort2 v = *reinterpret_cast<const ushort2*>(base + o * Hn);
            a0 += bf2f(v.x);
            a1 += bf2f(v.y);
        }
        float ss = a0 * a0 + a1 * a1;
#pragma unroll
        for (int off = 1; off < 64; off <<= 1) ss += __shfl_xor(ss, off);
        const float sc = 1.f / (sqrtf(ss) + 1e-30f);
        nbL[2 * lane]     = a0 * sc;
        nbL[2 * lane + 1] = a1 * sc;
    }
    __syncthreads();

    // --- p4: reduce+normalize slot1 (wave0) and slot2 (wave1) ---
    if (wv == 0) {
        float s0 = 0.f, s1 = 0.f;
#pragma unroll
        for (int q = 0; q < 4; ++q) {
            s0 += part1[q][2 * lane];
            s1 += part1[q][2 * lane + 1];
        }
        float ss = s0 * s0 + s1 * s1;
#pragma unroll
        for (int off = 1; off < 64; off <<= 1) ss += __shfl_xor(ss, off);
        const float sc = 1.f / (sqrtf(ss) + 1e-30f);
        nbL[128 + 2 * lane]     = s0 * sc;
        nbL[128 + 2 * lane + 1] = s1 * sc;
    } else if (wv == 1) {
        float s0 = 0.f, s1 = 0.f;
#pragma unroll
        for (int q = 0; q < 4; ++q) {
            s0 += part2[q][2 * lane];
            s1 += part2[q][2 * lane + 1];
        }
        float ss = s0 * s0 + s1 * s1;
#pragma unroll
        for (int off = 1; off < 64; off <<= 1) ss += __shfl_xor(ss, off);
        const float sc = 1.f / (sqrtf(ss) + 1e-30f);
        nbL[256 + 2 * lane]     = s0 * sc;
        nbL[256 + 2 * lane + 1] = s1 * sc;
    }
    __syncthreads();

    // --- p5: wide-load up-GEMV. thread (i=t&15, j=t>>4): 8 dims i*8..i*8+7,
    // k = r*16 + j over 24 rounds; uint4 load = 8 bf16 per round. ---
    {
        const int i8 = (t & 15) * 8, j = t >> 4;
        float a[8] = {};
#pragma unroll
        for (int r = 0; r < 24; ++r) {
            const int k = r * 16 + j;
            const uint4 w = *reinterpret_cast<const uint4*>(upWbf + (size_t)k * 128 + i8);
            const float x = nbL[k];
            a[0] = fmaf(x, bflo(w.x), a[0]); a[1] = fmaf(x, bfhi(w.x), a[1]);
            a[2] = fmaf(x, bflo(w.y), a[2]); a[3] = fmaf(x, bfhi(w.y), a[3]);
            a[4] = fmaf(x, bflo(w.z), a[4]); a[5] = fmaf(x, bfhi(w.z), a[5]);
            a[6] = fmaf(x, bflo(w.w), a[6]); a[7] = fmaf(x, bfhi(w.w), a[7]);
        }
#pragma unroll
        for (int q = 0; q < 8; ++q) gp16[j][i8 + q] = a[q];
    }
    __syncthreads();
    if (t < 128) {
        float g = upb[t];
#pragma unroll
        for (int j = 0; j < 16; ++j) g += gp16[j][t];
        g = fmaxf(g, 0.f);
        atomicAdd(&gwacc[b * 128 + t], g);
    }
}

// ---------------------------------------------------------------------------
// final4: read pooled sums, mean, two GEMVs, gates. 8 blocks x 128 thr.
// ---------------------------------------------------------------------------
__global__ __launch_bounds__(128) void final4_k(const int* __restrict__ wcnt,
                                                const float* __restrict__ gwacc,
                                                const float* __restrict__ nh,
                                                const float* __restrict__ wgW,
                                                const float* __restrict__ wgb,
                                                const float* __restrict__ fgW,
                                                const float* __restrict__ fgb,
                                                float* __restrict__ out) {
    const int b = blockIdx.x, t = threadIdx.x;
    __shared__ float gw[Dn], nhs[Dn];
    const float inv = 1.f / ((float)wcnt[b] + 1e-30f);
    gw[t]  = gwacc[b * Dn + t] * inv;
    nhs[t] = nh[b * Dn + t];
    __syncthreads();
    float gu = wgb[t];
    for (int d = 0; d < Dn; ++d) gu = fmaf(gw[d], wgW[d * Dn + t], gu);
    gu = fmaxf(gu, 0.f);
    float fg = fgb[t];
    for (int d = 0; d < Dn; ++d) fg = fmaf(gw[d], fgW[d * Dn + t], fg);
    for (int d = 0; d < Dn; ++d) fg = fmaf(nhs[d], fgW[(Dn + d) * Dn + t], fg);
    const float forget = 1.f / (1.f + expf(-fg));
    out[b * Dn + t] = fmaxf(forget, 0.1f) * nhs[t] + (1.f - forget) * gu;
}

// ---------------------------------------------------------------------------
extern "C" void kernel_launch(void* const* d_in, const int* in_sizes, int n_in,
                              void* d_out, int out_size, void* d_ws, size_t ws_size,
                              hipStream_t stream) {
    (void)in_sizes; (void)n_in; (void)out_size; (void)ws_size;
    const float* word_outputs        = (const float*)d_in[0];
    const float* node_hidden         = (const float*)d_in[1];
    const float* op_embedding        = (const float*)d_in[2];
    const float* word_operator       = (const float*)d_in[3];
    const float* word_word           = (const float*)d_in[4];
    const float* depend_relation     = (const float*)d_in[5];
    const float* word_exist_matrix   = (const float*)d_in[6];
    const float* word_exist_sequence = (const float*)d_in[7];
    const float* goal_word           = (const float*)d_in[8];
    const float* o_w_W = (const float*)d_in[9];
    const float* o_w_b = (const float*)d_in[10];
    const float* wk_W  = (const float*)d_in[11];
    const float* wk_b  = (const float*)d_in[12];
    const float* ws_W  = (const float*)d_in[13];
    const float* ws_b  = (const float*)d_in[14];
    const float* up_W  = (const float*)d_in[15];
    const float* up_b  = (const float*)d_in[16];
    const float* wg_W  = (const float*)d_in[17];
    const float* wg_b  = (const float*)d_in[18];
    const float* fg_W  = (const float*)d_in[19];
    const float* fg_b  = (const float*)d_in[20];
    float* out = (float*)d_out;

    char* ws = (char*)d_ws;
    unsigned short* oph   = (unsigned short*)(ws + 0);                      // 128 KB
    unsigned short* wkh   = (unsigned short*)(ws + (1u << 20));             // 4 MB
    unsigned short* wsh   = (unsigned short*)(ws + (5u << 20));             // 4 MB
    int* widx             = (int*)(ws + (9u << 20));                        // 16 KB
    int* wcnt             = (int*)(ws + (9u << 20) + 32768);                // 32 B
    float* gwacc          = (float*)(ws + (9u << 20) + 65536);              // 4 KB
    unsigned short* upWbf = (unsigned short*)(ws + (9u << 20) + 131072);    // 96 KB

    prep_k<<<275, 256, 0, stream>>>(word_outputs, wk_W, ws_W, wk_b, ws_b, wkh, wsh,
                                    op_embedding, o_w_W, o_w_b, oph,
                                    goal_word, word_exist_sequence, widx, wcnt, gwacc,
                                    up_W, upWbf);
    mega_agg7<<<4096, 256, 0, stream>>>(widx, wcnt, word_word, word_exist_matrix,
                                        depend_relation, word_operator, oph, wkh, wsh,
                                        upWbf, up_b, gwacc);
    final4_k<<<8, 128, 0, stream>>>(wcnt, gwacc, node_hidden,
                                    wg_W, wg_b, fg_W, fg_b, out);
}

// Round 16
// 333.960 us; speedup vs baseline: 1.0291x; 1.0055x over previous
//
#include <hip/hip_runtime.h>
#include <math.h>

#define Sn 4
#define Bn 8
#define Ln 512
#define Dn 128
#define Hn 128
#define NOPn 64
#define Wn 2048

// ESTABLISHED: inputs fp32 insertion order; output fp32; bf16-space compare
// (thr 3.6e-2); ws = 512MB; harness tax ~220-260us/iter; poison fill 78us.
// R21 354. R27 350.6 (bf16 upWbf). R28 345.0 (wide loads). R30 339.2 (XCD
// swizzle). R33 334.9 (BEST): dual GEMM -> bf16 MFMA. R35 335.8: oph-MFMA +
// float4 staging NEUTRAL (prep not on critical path; prep done). FAILS:
// R29/R31 (block shape), R32/R34 (ballot-walk), R22-R26 (in-kernel sync).
// MEGA shape frozen at R30; only proven lever family = widening (R28).
// R36 (this): p3 gathers widened once more -- quarter-wave per row
// (ql=lane>>4, c=lane&15, uint4 = 8 bf16/lane, 16 lanes/row) -> 16 rows in
// flight per block (was 8), half the p-loop trips. Reduce via
// shfl_xor(16)+shfl_xor(32). Everything else identical to R35.

__device__ __forceinline__ float bf2f(unsigned short u) {
    return __uint_as_float(((unsigned int)u) << 16);
}
__device__ __forceinline__ float bflo(unsigned int u) {
    return __uint_as_float(u << 16);
}
__device__ __forceinline__ float bfhi(unsigned int u) {
    return __uint_as_float(u & 0xFFFF0000u);
}
__device__ __forceinline__ unsigned short f2bf(float f) {
    unsigned int u = __float_as_uint(f);
    return (unsigned short)((u + 0x7FFFu + ((u >> 16) & 1u)) >> 16);  // RNE
}

typedef __attribute__((ext_vector_type(8))) short bf16x8;
typedef __attribute__((ext_vector_type(4))) float f32x4;

// ---------------------------------------------------------------------------
// prep_k: blockIdx branches.
//   0..255   : dual GEMM tile via bf16 MFMA (wkh/wsh from word_outputs)
//   256..263 : op-embedding GEMM tile via bf16 MFMA (oph)
//   264..271 : compact pooled indices for b = bid-264 (cap 512)
//   272      : zero gwacc
//   273..274 : convert upW (384x128 fp32) -> upWbf (bf16)
// ---------------------------------------------------------------------------
__global__ __launch_bounds__(256) void prep_k(const float* __restrict__ A,
                                              const float* __restrict__ W1,
                                              const float* __restrict__ W2,
                                              const float* __restrict__ b1,
                                              const float* __restrict__ b2,
                                              unsigned short* __restrict__ C1,
                                              unsigned short* __restrict__ C2,
                                              const float* __restrict__ ope,
                                              const float* __restrict__ owW,
                                              const float* __restrict__ owb,
                                              unsigned short* __restrict__ oph,
                                              const float* __restrict__ goal,
                                              const float* __restrict__ wes,
                                              int* __restrict__ widx,
                                              int* __restrict__ wcnt,
                                              float* __restrict__ gwacc,
                                              const float* __restrict__ upW,
                                              unsigned short* __restrict__ upWbf) {
    __shared__ __align__(16) unsigned char smem[33792];
    const int bid = blockIdx.x, tid = threadIdx.x;

    if (bid < 264) {  // ---- GEMM tiles via MFMA (dual for <256, single for oph) ----
        unsigned short (*WT)[132] = reinterpret_cast<unsigned short(*)[132]>(smem);
        const bool dual = bid < 256;
        const int m0 = dual ? bid * 64 : (bid - 256) * 64;
        const float* Asrc = dual ? A : ope;
        const int lane = tid & 63, wr = tid >> 6;
        const int rloc = lane & 15, bsel = lane >> 4;

        // hoist A fragments (row m0+wr*16+rloc), two-half k-layout per ks
        bf16x8 af[4];
        const float* Arow = Asrc + (size_t)(m0 + wr * 16 + rloc) * 128;
#pragma unroll
        for (int ks = 0; ks < 4; ++ks) {
            float4 a0 = *reinterpret_cast<const float4*>(Arow + ks * 32 + 4 * bsel);
            float4 a1 = *reinterpret_cast<const float4*>(Arow + ks * 32 + 16 + 4 * bsel);
            af[ks][0] = (short)f2bf(a0.x); af[ks][1] = (short)f2bf(a0.y);
            af[ks][2] = (short)f2bf(a0.z); af[ks][3] = (short)f2bf(a0.w);
            af[ks][4] = (short)f2bf(a1.x); af[ks][5] = (short)f2bf(a1.y);
            af[ks][6] = (short)f2bf(a1.z); af[ks][7] = (short)f2bf(a1.w);
        }

        const int nmat = dual ? 2 : 1;
        for (int mat = 0; mat < nmat; ++mat) {
            const float* Wsrc = dual ? (mat ? W2 : W1) : owW;
            const float* bias = dual ? (mat ? b2 : b1) : owb;
            unsigned short* Cdst = dual ? (mat ? C2 : C1) : oph;
            __syncthreads();  // protect WT before restage
            // float4 staging: 16 iters/thread, 1 vector load + 4 LDS writes
            for (int idx = tid * 4; idx < 128 * 128; idx += 1024) {
                const int k = idx >> 7, c = idx & 127;
                float4 v = *reinterpret_cast<const float4*>(Wsrc + (size_t)k * 128 + c);
                WT[c + 0][k] = f2bf(v.x);
                WT[c + 1][k] = f2bf(v.y);
                WT[c + 2][k] = f2bf(v.z);
                WT[c + 3][k] = f2bf(v.w);
            }
            __syncthreads();

            f32x4 acc[8];
#pragma unroll
            for (int tl = 0; tl < 8; ++tl) acc[tl] = (f32x4){0.f, 0.f, 0.f, 0.f};
#pragma unroll
            for (int ks = 0; ks < 4; ++ks) {
#pragma unroll
                for (int tl = 0; tl < 8; ++tl) {
                    const unsigned short* p = &WT[tl * 16 + rloc][ks * 32 + 4 * bsel];
                    bf16x8 bfv;
#pragma unroll
                    for (int j = 0; j < 4; ++j) {
                        bfv[j]     = (short)p[j];
                        bfv[4 + j] = (short)p[16 + j];
                    }
                    acc[tl] = __builtin_amdgcn_mfma_f32_16x16x32_bf16(
                        af[ks], bfv, acc[tl], 0, 0, 0);
                }
            }
            // C/D: col = lane&15, row = (lane>>4)*4 + q  [verified m89/m91]
#pragma unroll
            for (int tl = 0; tl < 8; ++tl) {
                const int col = tl * 16 + rloc;
                const float bv = bias[col];
#pragma unroll
                for (int q = 0; q < 4; ++q) {
                    const int row = m0 + wr * 16 + bsel * 4 + q;
                    Cdst[(size_t)row * 128 + col] = f2bf(acc[tl][q] + bv);
                }
            }
        }
    } else if (bid < 272) {  // ---- compact (cap 512) ----
        int* cnt = reinterpret_cast<int*>(smem);
        const int b = bid - 264;
        if (tid == 0) *cnt = 0;
        __syncthreads();
#pragma unroll
        for (int j = 0; j < 8; ++j) {
            const int w = tid * 8 + j;
            if (goal[b * Wn + w] != 0.f && wes[b * Wn + w] != 0.f) {
                const int p = atomicAdd(cnt, 1);
                if (p < 512) widx[b * 512 + p] = w;
            }
        }
        __syncthreads();
        if (tid == 0) wcnt[b] = *cnt < 512 ? *cnt : 512;
    } else if (bid == 272) {  // ---- zero gwacc ----
        for (int idx = tid; idx < 1024; idx += 256) gwacc[idx] = 0.f;
    } else {  // ---- upW -> bf16 (2 blocks, 24576 elems each) ----
        const int base = (bid - 273) * 24576;
        for (int e = base + tid * 4; e < base + 24576; e += 1024) {
            float4 v = *reinterpret_cast<const float4*>(upW + e);
            alignas(8) unsigned short u[4] = {f2bf(v.x), f2bf(v.y), f2bf(v.z), f2bf(v.w)};
            *reinterpret_cast<uint2*>(upWbf + e) = *reinterpret_cast<const uint2*>(u);
        }
    }
}

// ---------------------------------------------------------------------------
// mega_agg11: R30 shape; p3 gathers widened to quarter-wave/row:
// ql=lane>>4 picks one of 4 rows per wave per iteration (16 in flight per
// block), c=lane&15 covers dims c*8..c*8+7 via one uint4 (8 bf16).
// Reduction: shfl_xor(16)+shfl_xor(32); ql==0 lanes write part[wv].
// Everything else (scan, slot0, p4, p5) = R30 verbatim.
// ---------------------------------------------------------------------------
__global__ __launch_bounds__(256) void mega_agg11(const int* __restrict__ widx,
                                                  const int* __restrict__ wcnt,
                                                  const float* __restrict__ ww,
                                                  const float* __restrict__ wem,
                                                  const float* __restrict__ dep,
                                                  const float* __restrict__ wop,
                                                  const unsigned short* __restrict__ oph,
                                                  const unsigned short* __restrict__ wkh,
                                                  const unsigned short* __restrict__ wsh,
                                                  const unsigned short* __restrict__ upWbf,
                                                  const float* __restrict__ upb,
                                                  float* __restrict__ gwacc) {
    const int bid = blockIdx.x;
    const int b = bid & 7, i = bid >> 3;  // XCD swizzle: batch -> XCD
    if (i >= wcnt[b]) return;             // uniform exit
    const int w_dst = widx[b * 512 + i];
    const int t = threadIdx.x;
    const int lane = t & 63, wv = t >> 6;

    __shared__ int kidx[512];
    __shared__ int sidx[256];
    __shared__ int kn, sn;
    __shared__ float part1[4][128];
    __shared__ float part2[4][128];
    __shared__ float nbL[384];
    __shared__ float gp16[16][128];
    if (t == 0) { kn = 0; sn = 0; }
    __syncthreads();

    // --- p1: fused ww & wem row streams + dep row scan ---
    const float* wwr = ww  + ((size_t)(b * Wn + w_dst)) * Wn;
    const float* wmr = wem + ((size_t)(b * Wn + w_dst)) * Wn;
#pragma unroll
    for (int q = 0; q < 2; ++q) {
        const int e0 = q * 1024 + t * 4;
        float4 v = *reinterpret_cast<const float4*>(wwr + e0);
        float4 m = *reinterpret_cast<const float4*>(wmr + e0);
        float vv[4] = {v.x, v.y, v.z, v.w};
        float mm[4] = {m.x, m.y, m.z, m.w};
#pragma unroll
        for (int j = 0; j < 4; ++j)
            if (vv[j] != 0.f && mm[j] != 0.f) {
                int p = atomicAdd(&kn, 1);
                if (p < 512) kidx[p] = e0 + j;
            }
    }
    const int sD = w_dst >> 9, lD = w_dst & 511;
    if (t < 128) {
        const float* dr = dep + ((size_t)((sD * Bn + b) * Ln + lD)) * Ln + t * 4;
        float4 v = *reinterpret_cast<const float4*>(dr);
        float vv[4] = {v.x, v.y, v.z, v.w};
#pragma unroll
        for (int j = 0; j < 4; ++j)
            if (vv[j] != 0.f) {
                int p = atomicAdd(&sn, 1);
                if (p < 256) sidx[p] = t * 4 + j;
            }
    }
    float m_op = 0.f;
    if (wv == 3) m_op = wop[((size_t)(b * Wn + w_dst)) * NOPn + lane];
    __syncthreads();

    const int nk = kn < 512 ? kn : 512;
    const int ns = sn < 256 ? sn : 256;
    const int ql = lane >> 4, c = lane & 15;

    // --- p3: gathers (uint4 = 8 bf16/lane, 16 lanes/row, 4 rows/wave) ---
    {   // slot1
        float a[8] = {};
        for (int p = wv * 4 + ql; p < nk; p += 16) {
            const int w = kidx[p];
            const int s = w >> 9, l = w & 511;
            const uint4 x = *reinterpret_cast<const uint4*>(
                wkh + ((size_t)((s * Bn + b) * Ln + l)) * Hn + c * 8);
            a[0] += bflo(x.x); a[1] += bfhi(x.x);
            a[2] += bflo(x.y); a[3] += bfhi(x.y);
            a[4] += bflo(x.z); a[5] += bfhi(x.z);
            a[6] += bflo(x.w); a[7] += bfhi(x.w);
        }
#pragma unroll
        for (int q = 0; q < 8; ++q) {
            a[q] += __shfl_xor(a[q], 16);
            a[q] += __shfl_xor(a[q], 32);
        }
        if (ql == 0) {
#pragma unroll
            for (int q = 0; q < 8; ++q) part1[wv][c * 8 + q] = a[q];
        }
    }
    {   // slot2
        const unsigned short* base = wsh + (size_t)((sD * Bn + b) * Ln) * Hn + c * 8;
        float a[8] = {};
        for (int p = wv * 4 + ql; p < ns; p += 16) {
            const uint4 x = *reinterpret_cast<const uint4*>(base + (size_t)sidx[p] * Hn);
            a[0] += bflo(x.x); a[1] += bfhi(x.x);
            a[2] += bflo(x.y); a[3] += bfhi(x.y);
            a[4] += bflo(x.z); a[5] += bfhi(x.z);
            a[6] += bflo(x.w); a[7] += bfhi(x.w);
        }
#pragma unroll
        for (int q = 0; q < 8; ++q) {
            a[q] += __shfl_xor(a[q], 16);
            a[q] += __shfl_xor(a[q], 32);
        }
        if (ql == 0) {
#pragma unroll
            for (int q = 0; q < 8; ++q) part2[wv][c * 8 + q] = a[q];
        }
    }
    if (wv == 3) {  // slot0 -> nbL[0:128]
        unsigned long long bal = __ballot(m_op != 0.f);
        float a0 = 0.f, a1 = 0.f;
        const unsigned short* base = oph + (size_t)b * NOPn * Hn + 2 * lane;
        while (bal) {
            const int o = __ffsll(bal) - 1;
            bal &= bal - 1;
            ushort2 v = *reinterpret_cast<const ushort2*>(base + o * Hn);
            a0 += bf2f(v.x);
            a1 += bf2f(v.y);
        }
        float ss = a0 * a0 + a1 * a1;
#pragma unroll
        for (int off = 1; off < 64; off <<= 1) ss += __shfl_xor(ss, off);
        const float sc = 1.f / (sqrtf(ss) + 1e-30f);
        nbL[2 * lane]     = a0 * sc;
        nbL[2 * lane + 1] = a1 * sc;
    }
    __syncthreads();

    // --- p4: reduce+normalize slot1 (wave0) and slot2 (wave1) ---
    if (wv == 0) {
        float s0 = 0.f, s1 = 0.f;
#pragma unroll
        for (int q = 0; q < 4; ++q) {
            s0 += part1[q][2 * lane];
            s1 += part1[q][2 * lane + 1];
        }
        float ss = s0 * s0 + s1 * s1;
#pragma unroll
        for (int off = 1; off < 64; off <<= 1) ss += __shfl_xor(ss, off);
        const float sc = 1.f / (sqrtf(ss) + 1e-30f);
        nbL[128 + 2 * lane]     = s0 * sc;
        nbL[128 + 2 * lane + 1] = s1 * sc;
    } else if (wv == 1) {
        float s0 = 0.f, s1 = 0.f;
#pragma unroll
        for (int q = 0; q < 4; ++q) {
            s0 += part2[q][2 * lane];
            s1 += part2[q][2 * lane + 1];
        }
        float ss = s0 * s0 + s1 * s1;
#pragma unroll
        for (int off = 1; off < 64; off <<= 1) ss += __shfl_xor(ss, off);
        const float sc = 1.f / (sqrtf(ss) + 1e-30f);
        nbL[256 + 2 * lane]     = s0 * sc;
        nbL[256 + 2 * lane + 1] = s1 * sc;
    }
    __syncthreads();

    // --- p5: wide-load up-GEMV. thread (i=t&15, j=t>>4): 8 dims i*8..i*8+7,
    // k = r*16 + j over 24 rounds; uint4 load = 8 bf16 per round. ---
    {
        const int i8 = (t & 15) * 8, j = t >> 4;
        float a[8] = {};
#pragma unroll
        for (int r = 0; r < 24; ++r) {
            const int k = r * 16 + j;
            const uint4 w = *reinterpret_cast<const uint4*>(upWbf + (size_t)k * 128 + i8);
            const float x = nbL[k];
            a[0] = fmaf(x, bflo(w.x), a[0]); a[1] = fmaf(x, bfhi(w.x), a[1]);
            a[2] = fmaf(x, bflo(w.y), a[2]); a[3] = fmaf(x, bfhi(w.y), a[3]);
            a[4] = fmaf(x, bflo(w.z), a[4]); a[5] = fmaf(x, bfhi(w.z), a[5]);
            a[6] = fmaf(x, bflo(w.w), a[6]); a[7] = fmaf(x, bfhi(w.w), a[7]);
        }
#pragma unroll
        for (int q = 0; q < 8; ++q) gp16[j][i8 + q] = a[q];
    }
    __syncthreads();
    if (t < 128) {
        float g = upb[t];
#pragma unroll
        for (int j = 0; j < 16; ++j) g += gp16[j][t];
        g = fmaxf(g, 0.f);
        atomicAdd(&gwacc[b * 128 + t], g);
    }
}

// ---------------------------------------------------------------------------
// final4: read pooled sums, mean, two GEMVs, gates. 8 blocks x 128 thr.
// ---------------------------------------------------------------------------
__global__ __launch_bounds__(128) void final4_k(const int* __restrict__ wcnt,
                                                const float* __restrict__ gwacc,
                                                const float* __restrict__ nh,
                                                const float* __restrict__ wgW,
                                                const float* __restrict__ wgb,
                                                const float* __restrict__ fgW,
                                                const float* __restrict__ fgb,
                                                float* __restrict__ out) {
    const int b = blockIdx.x, t = threadIdx.x;
    __shared__ float gw[Dn], nhs[Dn];
    const float inv = 1.f / ((float)wcnt[b] + 1e-30f);
    gw[t]  = gwacc[b * Dn + t] * inv;
    nhs[t] = nh[b * Dn + t];
    __syncthreads();
    float gu = wgb[t];
    for (int d = 0; d < Dn; ++d) gu = fmaf(gw[d], wgW[d * Dn + t], gu);
    gu = fmaxf(gu, 0.f);
    float fg = fgb[t];
    for (int d = 0; d < Dn; ++d) fg = fmaf(gw[d], fgW[d * Dn + t], fg);
    for (int d = 0; d < Dn; ++d) fg = fmaf(nhs[d], fgW[(Dn + d) * Dn + t], fg);
    const float forget = 1.f / (1.f + expf(-fg));
    out[b * Dn + t] = fmaxf(forget, 0.1f) * nhs[t] + (1.f - forget) * gu;
}

// ---------------------------------------------------------------------------
extern "C" void kernel_launch(void* const* d_in, const int* in_sizes, int n_in,
                              void* d_out, int out_size, void* d_ws, size_t ws_size,
                              hipStream_t stream) {
    (void)in_sizes; (void)n_in; (void)out_size; (void)ws_size;
    const float* word_outputs        = (const float*)d_in[0];
    const float* node_hidden         = (const float*)d_in[1];
    const float* op_embedding        = (const float*)d_in[2];
    const float* word_operator       = (const float*)d_in[3];
    const float* word_word           = (const float*)d_in[4];
    const float* depend_relation     = (const float*)d_in[5];
    const float* word_exist_matrix   = (const float*)d_in[6];
    const float* word_exist_sequence = (const float*)d_in[7];
    const float* goal_word           = (const float*)d_in[8];
    const float* o_w_W = (const float*)d_in[9];
    const float* o_w_b = (const float*)d_in[10];
    const float* wk_W  = (const float*)d_in[11];
    const float* wk_b  = (const float*)d_in[12];
    const float* ws_W  = (const float*)d_in[13];
    const float* ws_b  = (const float*)d_in[14];
    const float* up_W  = (const float*)d_in[15];
    const float* up_b  = (const float*)d_in[16];
    const float* wg_W  = (const float*)d_in[17];
    const float* wg_b  = (const float*)d_in[18];
    const float* fg_W  = (const float*)d_in[19];
    const float* fg_b  = (const float*)d_in[20];
    float* out = (float*)d_out;

    char* ws = (char*)d_ws;
    unsigned short* oph   = (unsigned short*)(ws + 0);                      // 128 KB
    unsigned short* wkh   = (unsigned short*)(ws + (1u << 20));             // 4 MB
    unsigned short* wsh   = (unsigned short*)(ws + (5u << 20));             // 4 MB
    int* widx             = (int*)(ws + (9u << 20));                        // 16 KB
    int* wcnt             = (int*)(ws + (9u << 20) + 32768);                // 32 B
    float* gwacc          = (float*)(ws + (9u << 20) + 65536);              // 4 KB
    unsigned short* upWbf = (unsigned short*)(ws + (9u << 20) + 131072);    // 96 KB

    prep_k<<<275, 256, 0, stream>>>(word_outputs, wk_W, ws_W, wk_b, ws_b, wkh, wsh,
                                    op_embedding, o_w_W, o_w_b, oph,
                                    goal_word, word_exist_sequence, widx, wcnt, gwacc,
                                    up_W, upWbf);
    mega_agg11<<<4096, 256, 0, stream>>>(widx, wcnt, word_word, word_exist_matrix,
                                         depend_relation, word_operator, oph, wkh, wsh,
                                         upWbf, up_b, gwacc);
    final4_k<<<8, 128, 0, stream>>>(wcnt, gwacc, node_hidden,
                                    wg_W, wg_b, fg_W, fg_b, out);
}